// Round 6
// baseline (742.921 us; speedup 1.0000x reference)
//
#include <hip/hip_runtime.h>
#include <math.h>

#define T_TOKENS 8192
#define HID      4096
#define NEXP     512
#define TOPK     12
#define RSCALE   2.5f

// ---------------- shared helpers (verified round 1) ----------------

__device__ __forceinline__ unsigned int fkey(float f) {
    unsigned int u = __float_as_uint(f);
    return (u & 0x80000000u) ? ~u : (u | 0x80000000u);  // monotonic float->uint
}

__device__ __forceinline__ float pick8(const float* p, int j) {
    float v = p[0];
    if (j == 1) v = p[1];
    if (j == 2) v = p[2];
    if (j == 3) v = p[3];
    if (j == 4) v = p[4];
    if (j == 5) v = p[5];
    if (j == 6) v = p[6];
    if (j == 7) v = p[7];
    return v;
}

// ================== fp16x3 split-precision common (verified rounds 3-5) ==================
// x = xh + 2^-12 xl + O(2^-22 x)   (RNE hi, RNE scaled residual)
// logits*64 = accH(xh*wh) + 2^-12 * accC(xh*wl + xl*wh), W pre-scaled *64.

typedef __attribute__((ext_vector_type(8))) _Float16 f16x8;
typedef __attribute__((ext_vector_type(4))) float    f32x4;

#define ROWW 144   // W LDS row: 64 B hi plane | 16 B pad | 64 B lo plane

// float4 -> 4 packed hi halves (uint2) + 4 packed scaled-lo halves (uint2), RNE
__device__ __forceinline__ void cvt4(const float4 f, uint2& h, uint2& l) {
    _Float16 h0 = (_Float16)f.x, h1 = (_Float16)f.y;
    _Float16 h2 = (_Float16)f.z, h3 = (_Float16)f.w;
    float r0 = (f.x - (float)h0) * 4096.f;
    float r1 = (f.y - (float)h1) * 4096.f;
    float r2 = (f.z - (float)h2) * 4096.f;
    float r3 = (f.w - (float)h3) * 4096.f;
    _Float16 l0 = (_Float16)r0, l1 = (_Float16)r1;
    _Float16 l2 = (_Float16)r2, l3 = (_Float16)r3;
    union P { _Float16 q[2]; unsigned int u; } p;
    p.q[0] = h0; p.q[1] = h1; h.x = p.u;
    p.q[0] = h2; p.q[1] = h3; h.y = p.u;
    p.q[0] = l0; p.q[1] = l1; l.x = p.u;
    p.q[0] = l2; p.q[1] = l3; l.y = p.u;
}

// floats [a|b] (k-order 0..7) -> f16x8 hi / f16x8 lo (verified round 5)
__device__ __forceinline__ void cvt8(const float4 a, const float4 b, f16x8& hi, f16x8& lo) {
    union U { f16x8 v; uint2 u[2]; } H, L;
    uint2 h0, l0, h1, l1;
    cvt4(a, h0, l0);
    cvt4(b, h1, l1);
    H.u[0] = h0; H.u[1] = h1;
    L.u[0] = l0; L.u[1] = l1;
    hi = H.v; lo = L.v;
}

__device__ __forceinline__ float4 scale64(const float4 f) {
    return make_float4(f.x * 64.f, f.y * 64.f, f.z * 64.f, f.w * 64.f);
}

// ================== fused kernel: GEMM tile + ticketed top-k ==================
// Grid 512: m_grp 0..63 (128 tokens), n_grp 0..7 (64 experts). All 8 n-blocks of an
// m-group land on one XCD (blockIdx%8 swizzle) -> logit exchange stays in that L2.
// Wave w: tokens [w*32, w*32+32) x all 64 experts. W planes double-buffered in LDS
// (inline fp32->fp16 conversion, 1 barrier/iter); A fragments from global + reg dbuf.
// Last-arriving block of each m-group (device atomic ticket) runs the round-1-verified
// softmax + biased top-12 for its 128 tokens.

__launch_bounds__(256, 2)
__global__ void fused2_kernel(const float* __restrict__ X,
                              const float* __restrict__ W,
                              const float* __restrict__ bias,
                              float* __restrict__ logits,
                              int* __restrict__ ticket,
                              float* __restrict__ out)
{
    __shared__ __align__(16) unsigned char Wb[2][64 * ROWW];   // 18 KB
    __shared__ int lastflag;

    const int tid  = threadIdx.x;
    const int lane = tid & 63;
    const int w    = tid >> 6;

    const int x8    = blockIdx.x & 7;
    const int i64   = blockIdx.x >> 3;        // 0..63
    const int m_grp = x8 * 8 + (i64 >> 3);    // 0..63
    const int n_grp = i64 & 7;                // 0..7
    const int tok0  = m_grp * 128;
    const int e0    = n_grp * 64;

    const int m16 = lane & 15;
    const int q   = lane >> 4;
    const int waveM = w * 32;

    // W staging: 2 float4/thread per iter. slot s in {0,1}: row = s*32 + (tid>>3), grp = tid&7
    const int sr = tid >> 3;                  // 0..31
    const int sg = tid & 7;                   // 0..7
    const float* wp0 = W + (size_t)(e0 + sr) * HID + sg * 4;
    const float* wp1 = W + (size_t)(e0 + 32 + sr) * HID + sg * 4;
    unsigned char* wb0h = nullptr;            // computed per-iter below

    // A rows for this lane (round-5 verified pattern + waveM)
    const float* xr0 = X + (size_t)(tok0 + waveM + m16) * HID + q * 8;
    const float* xr1 = X + (size_t)(tok0 + waveM + 16 + m16) * HID + q * 8;

    // ---- preamble: tile kc=0 ----
    float4 a00 = *(const float4*)(xr0);
    float4 a01 = *(const float4*)(xr0 + 4);
    float4 a10 = *(const float4*)(xr1);
    float4 a11 = *(const float4*)(xr1 + 4);
    {
        const float4 w0 = *(const float4*)(wp0);
        const float4 w1 = *(const float4*)(wp1);
        uint2 h, l;
        cvt4(scale64(w0), h, l);
        *(uint2*)(&Wb[0][sr * ROWW + sg * 8])        = h;
        *(uint2*)(&Wb[0][sr * ROWW + 80 + sg * 8])   = l;
        cvt4(scale64(w1), h, l);
        *(uint2*)(&Wb[0][(32 + sr) * ROWW + sg * 8])      = h;
        *(uint2*)(&Wb[0][(32 + sr) * ROWW + 80 + sg * 8]) = l;
    }

    f32x4 accH[2][4], accC[2][4];
    #pragma unroll
    for (int mi = 0; mi < 2; mi++)
        #pragma unroll
        for (int ni = 0; ni < 4; ni++) { accH[mi][ni] = (f32x4)0.f; accC[mi][ni] = (f32x4)0.f; }

    #pragma unroll 1
    for (int kc = 0; kc < HID / 32; kc++) {
        const int cur = kc & 1;

        // prefetch next tile (global->reg), latency hidden under this iter's compute
        float4 nwa, nwb, n00, n01, n10, n11;
        if (kc + 1 < HID / 32) {
            const int off = (kc + 1) * 32;
            nwa = *(const float4*)(wp0 + off);
            nwb = *(const float4*)(wp1 + off);
            n00 = *(const float4*)(xr0 + off);
            n01 = *(const float4*)(xr0 + off + 4);
            n10 = *(const float4*)(xr1 + off);
            n11 = *(const float4*)(xr1 + off + 4);
        }

        // convert current A regs -> fragments (VALU, no LDS)
        f16x8 Ah[2], Al[2];
        cvt8(a00, a01, Ah[0], Al[0]);
        cvt8(a10, a11, Ah[1], Al[1]);

        __syncthreads();   // Wb[cur] fully written (prev iter / preamble); prev reads done

        // B fragments from Wb[cur] (round-3 verified addressing)
        f16x8 Bh[4], Bl[4];
        #pragma unroll
        for (int ni = 0; ni < 4; ni++) {
            const unsigned char* pr = &Wb[cur][(ni * 16 + m16) * ROWW + q * 16];
            Bh[ni] = *(const f16x8*)pr;
            Bl[ni] = *(const f16x8*)(pr + 80);
        }

        #pragma unroll
        for (int mi = 0; mi < 2; mi++)
            #pragma unroll
            for (int ni = 0; ni < 4; ni++) {
                accH[mi][ni] = __builtin_amdgcn_mfma_f32_16x16x32_f16(Ah[mi], Bh[ni], accH[mi][ni], 0, 0, 0);
                accC[mi][ni] = __builtin_amdgcn_mfma_f32_16x16x32_f16(Ah[mi], Bl[ni], accC[mi][ni], 0, 0, 0);
                accC[mi][ni] = __builtin_amdgcn_mfma_f32_16x16x32_f16(Al[mi], Bh[ni], accC[mi][ni], 0, 0, 0);
            }

        // stage next W tile into the other buffer (reads of Wb[cur^1] finished before
        // this iter's barrier); ds_writes drain at next iter's barrier
        if (kc + 1 < HID / 32) {
            unsigned char* dst = &Wb[cur ^ 1][0];
            uint2 h, l;
            cvt4(scale64(nwa), h, l);
            *(uint2*)(dst + sr * ROWW + sg * 8)        = h;
            *(uint2*)(dst + sr * ROWW + 80 + sg * 8)   = l;
            cvt4(scale64(nwb), h, l);
            *(uint2*)(dst + (32 + sr) * ROWW + sg * 8)      = h;
            *(uint2*)(dst + (32 + sr) * ROWW + 80 + sg * 8) = l;
            a00 = n00; a01 = n01; a10 = n10; a11 = n11;
        }
    }

    // ---- store logit tile. C/D layout (verified m89/m91): col = lane&15, row = q*4 + reg
    #pragma unroll
    for (int mi = 0; mi < 2; mi++)
        #pragma unroll
        for (int ni = 0; ni < 4; ni++) {
            const int e = e0 + ni * 16 + m16;
            #pragma unroll
            for (int r = 0; r < 4; r++) {
                const int token = tok0 + waveM + mi * 16 + q * 4 + r;
                logits[(size_t)token * NEXP + e] =
                    (accH[mi][ni][r] + accC[mi][ni][r] * (1.f / 4096.f)) * (1.f / 64.f);
            }
        }

    // ---- ticket: last of the 8 n-blocks for this m-group runs the top-k ----
    __threadfence();        // release: logit stores visible device-wide
    __syncthreads();
    if (tid == 0) {
        const int old = atomicAdd(&ticket[m_grp], 1);
        lastflag = (old == 7);
    }
    __syncthreads();
    if (!lastflag) return;
    __threadfence();        // acquire: safe even if XCD mapping heuristic changes

    // ---- softmax + biased top-12 (round-1 verified math), 32 tokens per wave ----
    const float4 bs0 = *(const float4*)&bias[4 * lane];
    const float4 bs1 = *(const float4*)&bias[256 + 4 * lane];
    const float br[8] = {bs0.x, bs0.y, bs0.z, bs0.w, bs1.x, bs1.y, bs1.z, bs1.w};

    for (int t = 0; t < 32; t++) {
        const int tok = tok0 + w * 32 + t;

        const float4 z0 = *(const float4*)&logits[(size_t)tok * NEXP + 4 * lane];
        const float4 z1 = *(const float4*)&logits[(size_t)tok * NEXP + 256 + 4 * lane];
        float z[8] = {z0.x, z0.y, z0.z, z0.w, z1.x, z1.y, z1.z, z1.w};

        float m = z[0];
        #pragma unroll
        for (int j = 1; j < 8; j++) m = fmaxf(m, z[j]);
        #pragma unroll
        for (int off = 32; off >= 1; off >>= 1) m = fmaxf(m, __shfl_xor(m, off));

        float p[8];
        float s = 0.f;
        #pragma unroll
        for (int j = 0; j < 8; j++) { p[j] = expf(z[j] - m); s += p[j]; }
        #pragma unroll
        for (int off = 32; off >= 1; off >>= 1) s += __shfl_xor(s, off);
        const float inv = 1.f / s;

        float pb[8], bb[8];
        #pragma unroll
        for (int j = 0; j < 8; j++) {
            pb[j] = p[j] * inv;
            bb[j] = pb[j] + br[j];
        }

        for (int kk = 0; kk < TOPK; kk++) {
            unsigned long long key = 0ull;
            #pragma unroll
            for (int j = 0; j < 8; j++) {
                int e = (j < 4) ? (4 * lane + j) : (256 + 4 * lane + (j - 4));
                unsigned long long k64 =
                    ((unsigned long long)fkey(bb[j]) << 32) |
                    (unsigned long long)(unsigned int)(1023 - e);
                key = (k64 > key) ? k64 : key;
            }
            #pragma unroll
            for (int off = 32; off >= 1; off >>= 1) {
                unsigned long long o = __shfl_xor(key, off);
                key = (o > key) ? o : key;
            }
            const int estar = 1023 - (int)(unsigned int)(key & 0xffffffffull);

            int lstar, jstar;
            if (estar < 256) { lstar = estar >> 2;         jstar = estar & 3; }
            else             { lstar = (estar - 256) >> 2; jstar = 4 + ((estar - 256) & 3); }

            const float pj   = pick8(pb, jstar);
            const float psel = __shfl(pj, lstar);

            if (lane == lstar) {
                if (jstar == 0) bb[0] = -INFINITY;
                if (jstar == 1) bb[1] = -INFINITY;
                if (jstar == 2) bb[2] = -INFINITY;
                if (jstar == 3) bb[3] = -INFINITY;
                if (jstar == 4) bb[4] = -INFINITY;
                if (jstar == 5) bb[5] = -INFINITY;
                if (jstar == 6) bb[6] = -INFINITY;
                if (jstar == 7) bb[7] = -INFINITY;
            }

            if (lane == 0) {
                out[(size_t)tok * TOPK + kk] = psel * RSCALE;
                out[(size_t)T_TOKENS * TOPK + (size_t)tok * TOPK + kk] = (float)estar;
            }
        }
    }
}

// ================== Fallback: round-1 fused fp32 kernel (verified) ==================

#define TM   32
#define BK   16
#define EPAD (NEXP + 4)
#define XPAD 36

__launch_bounds__(256, 1)
__global__ void router_kernel(const float* __restrict__ X,
                              const float* __restrict__ W,
                              const float* __restrict__ bias,
                              float* __restrict__ out)
{
    __shared__ float Wsh[BK][EPAD];
    __shared__ float Xsh[BK][XPAD];

    const int tid  = threadIdx.x;
    const int lane = tid & 63;
    const int wave = tid >> 6;
    const int tok0 = blockIdx.x * TM;

    float acc[8][8];
    #pragma unroll
    for (int i = 0; i < 8; i++)
        #pragma unroll
        for (int j = 0; j < 8; j++) acc[i][j] = 0.f;

    const int xt = tid >> 4;
    const int xk = tid & 15;

    for (int k0 = 0; k0 < HID; k0 += BK) {
        #pragma unroll
        for (int r = 0; r < 2; r++) {
            int t = r * 16 + xt;
            Xsh[xk][t] = X[(size_t)(tok0 + t) * HID + k0 + xk];
        }
        #pragma unroll
        for (int r = 0; r < 8; r++) {
            int flat4 = r * 256 + tid;
            int e  = flat4 >> 2;
            int kq = (flat4 & 3) * 4;
            const float4 wv = *(const float4*)&W[(size_t)e * HID + k0 + kq];
            Wsh[kq + 0][e] = wv.x;
            Wsh[kq + 1][e] = wv.y;
            Wsh[kq + 2][e] = wv.z;
            Wsh[kq + 3][e] = wv.w;
        }
        __syncthreads();

        #pragma unroll
        for (int k = 0; k < BK; k++) {
            float4 b0 = *(const float4*)&Wsh[k][4 * lane];
            float4 b1 = *(const float4*)&Wsh[k][256 + 4 * lane];
            float4 a0 = *(const float4*)&Xsh[k][wave * 8];
            float4 a1 = *(const float4*)&Xsh[k][wave * 8 + 4];
            float a[8] = {a0.x, a0.y, a0.z, a0.w, a1.x, a1.y, a1.z, a1.w};
            float b[8] = {b0.x, b0.y, b0.z, b0.w, b1.x, b1.y, b1.z, b1.w};
            #pragma unroll
            for (int i = 0; i < 8; i++)
                #pragma unroll
                for (int j = 0; j < 8; j++)
                    acc[i][j] = fmaf(a[i], b[j], acc[i][j]);
        }
        __syncthreads();
    }

    const float4 bs0 = *(const float4*)&bias[4 * lane];
    const float4 bs1 = *(const float4*)&bias[256 + 4 * lane];
    const float br[8] = {bs0.x, bs0.y, bs0.z, bs0.w, bs1.x, bs1.y, bs1.z, bs1.w};

    for (int i = 0; i < 8; i++) {
        const int tok = tok0 + wave * 8 + i;

        float m = acc[i][0];
        #pragma unroll
        for (int j = 1; j < 8; j++) m = fmaxf(m, acc[i][j]);
        #pragma unroll
        for (int off = 32; off >= 1; off >>= 1) m = fmaxf(m, __shfl_xor(m, off));

        float p[8];
        float s = 0.f;
        #pragma unroll
        for (int j = 0; j < 8; j++) { p[j] = expf(acc[i][j] - m); s += p[j]; }
        #pragma unroll
        for (int off = 32; off >= 1; off >>= 1) s += __shfl_xor(s, off);
        const float inv = 1.f / s;

        float pb[8], bb[8];
        #pragma unroll
        for (int j = 0; j < 8; j++) {
            pb[j] = p[j] * inv;
            bb[j] = pb[j] + br[j];
        }

        for (int kk = 0; kk < TOPK; kk++) {
            unsigned long long key = 0ull;
            #pragma unroll
            for (int j = 0; j < 8; j++) {
                int e = (j < 4) ? (4 * lane + j) : (256 + 4 * lane + (j - 4));
                unsigned long long k64 =
                    ((unsigned long long)fkey(bb[j]) << 32) |
                    (unsigned long long)(unsigned int)(1023 - e);
                key = (k64 > key) ? k64 : key;
            }
            #pragma unroll
            for (int off = 32; off >= 1; off >>= 1) {
                unsigned long long o = __shfl_xor(key, off);
                key = (o > key) ? o : key;
            }
            const int estar = 1023 - (int)(unsigned int)(key & 0xffffffffull);

            int lstar, jstar;
            if (estar < 256) { lstar = estar >> 2;         jstar = estar & 3; }
            else             { lstar = (estar - 256) >> 2; jstar = 4 + ((estar - 256) & 3); }

            const float pj   = pick8(pb, jstar);
            const float psel = __shfl(pj, lstar);

            if (lane == lstar) {
                if (jstar == 0) bb[0] = -INFINITY;
                if (jstar == 1) bb[1] = -INFINITY;
                if (jstar == 2) bb[2] = -INFINITY;
                if (jstar == 3) bb[3] = -INFINITY;
                if (jstar == 4) bb[4] = -INFINITY;
                if (jstar == 5) bb[5] = -INFINITY;
                if (jstar == 6) bb[6] = -INFINITY;
                if (jstar == 7) bb[7] = -INFINITY;
            }

            if (lane == 0) {
                out[(size_t)tok * TOPK + kk] = psel * RSCALE;
                out[(size_t)T_TOKENS * TOPK + (size_t)tok * TOPK + kk] = (float)estar;
            }
        }
    }
}

// ================== launcher ==================

extern "C" void kernel_launch(void* const* d_in, const int* in_sizes, int n_in,
                              void* d_out, int out_size, void* d_ws, size_t ws_size,
                              hipStream_t stream)
{
    const float* X    = (const float*)d_in[0];   // [8192, 4096]
    const float* W    = (const float*)d_in[1];   // [512, 4096]
    const float* bias = (const float*)d_in[2];   // [512]
    float* out = (float*)d_out;

    const size_t logits_bytes = (size_t)T_TOKENS * NEXP * sizeof(float);   // 16 MB
    const size_t need = logits_bytes + 64 * sizeof(int);

    if (ws_size >= need) {
        float* logits = (float*)d_ws;
        int* ticket   = (int*)((char*)d_ws + logits_bytes);
        hipMemsetAsync(ticket, 0, 64 * sizeof(int), stream);   // tickets zeroed each call
        fused2_kernel<<<dim3(512), dim3(256), 0, stream>>>(X, W, bias, logits, ticket, out);
    } else {
        router_kernel<<<dim3(T_TOKENS / TM), dim3(256), 0, stream>>>(X, W, bias, out);
    }
}